// Round 10
// baseline (127.021 us; speedup 1.0000x reference)
//
#include <hip/hip_runtime.h>

// GCN layer: out = relu( segment_mean(feature[edge_src], edge_dst) @ W^T + b )
// N=100000 nodes, E=1200000 edges, 64 feats in/out, all f32.
//
// Round 24: r23 frame (best measured, 126.13us) + ONE variable: aggregate
// phases 1-3 (mapRead binary search x2, window scan, rank+scatter) replaced
// by a direct cooperative region copy. The src-window sort measured NEUTRAL
// (r22==r15), so lsrc only needs to exist, not be sorted: each of the 256
// build-block regions is contiguous in binned[] and its lsrc span is known
// from the phase-0 scan (runL). 4 threads/region copy edges + build deg[]
// in one pass. Eliminates 16 dependent LDS reads/thread (binary searches),
// one 128-wide scan, one scatter pass, and 2 barriers. Gather: r23's 4-deep
// pipelined fixed-point LDS-atomic loop (bit-exact; int adds commute).

typedef __attribute__((ext_vector_type(8))) short short8;   // 8 bf16
typedef __attribute__((ext_vector_type(4))) float floatx4;  // MFMA acc

constexpr int kNodes = 100000;
constexpr int kEdges = 1200000;

constexpr int kBuckets = 1024;
constexpr int kBucketNodes = 98;                    // 1024*98 = 100352 >= N

constexpr int kBinBlocks = 256;
constexpr int kEdgesPerBlock = 4688;                // 256*4688 = 1200128 >= E
constexpr int kEPT = (kEdgesPerBlock + 1023) / 1024; // 5

constexpr int kCap = 2048;        // max edges/bucket (mean 1172, ~26 sigma)
constexpr float kFxScale = 262144.0f;   // 2^18 fixed-point scale
constexpr int kAccStride = 68;    // adds at {c,16+c,32+c,48+c}

// Workspace layout (int elements). Total ~18.7 MB.
constexpr int kWsFeat   = 0;                        // uint2[1600000] (12.8MB)
constexpr int kWsOff    = 3200000;                  // int[256][1025] row-major
constexpr int kWsBinned = kWsOff + kBinBlocks * (kBuckets + 1);  // int[256*4688]

__device__ __forceinline__ unsigned bf16rne(float f) {
  unsigned u = __float_as_uint(f);
  return (u + 0x7fffu + ((u >> 16) & 1u)) >> 16;  // round-to-nearest-even
}

// ---------------------------------------------------------------------------
// Kernel 1: feature conversion + single-pass deterministic bucket binning.
// (r15/r22/r23 verbatim)
// ---------------------------------------------------------------------------
__global__ __launch_bounds__(1024) void gcn_build(
    const float* __restrict__ feat,
    const int* __restrict__ src, const int* __restrict__ dst,
    int* __restrict__ ws) {
  uint2* fb16 = (uint2*)(ws + kWsFeat);
  int* offT   = ws + kWsOff;
  int* binned = ws + kWsBinned;

  __shared__ int lhist[kBuckets];
  __shared__ int lcur[kBuckets];
  __shared__ int wsum[16];

  const int tid = threadIdx.x;
  lhist[tid] = 0;
  __syncthreads();

  // ---- edge slice load + bucket histogram ----
  const int e0 = blockIdx.x * kEdgesPerBlock;
  const int cnt = min(kEdgesPerBlock, kEdges - e0);   // last block: 4560
  int es[kEPT], ebk[kEPT], edl[kEPT];
  #pragma unroll
  for (int k = 0; k < kEPT; ++k) {
    const int j = tid + k * 1024;
    if (j < cnt) {
      es[k] = src[e0 + j];
      const int d = dst[e0 + j];
      const int bk = d / kBucketNodes;      // magic-multiply const div
      ebk[k] = bk;
      edl[k] = d - bk * kBucketNodes;
      atomicAdd(&lhist[bk], 1);
    }
  }

  // ---- feature f32 -> permuted bf16 (independent; overlaps hist latency) ----
  const int t = blockIdx.x * 1024 + tid;
  for (int i = t; i < kNodes * 16; i += kBinBlocks * 1024) {
    const float* fr = feat + (size_t)(i >> 4) * 64 + (i & 15);
    uint2 p;
    p.x = bf16rne(fr[0])  | (bf16rne(fr[16]) << 16);
    p.y = bf16rne(fr[32]) | (bf16rne(fr[48]) << 16);
    fb16[i] = p;
  }
  __syncthreads();

  // ---- two-level shfl exclusive scan over 1024 counts ----
  const int own = lhist[tid];
  const int wv = tid >> 6, ln = tid & 63;
  int sc = own;
  #pragma unroll
  for (int off = 1; off < 64; off <<= 1) {
    const int v = __shfl_up(sc, off, 64);
    if (ln >= off) sc += v;
  }
  if (ln == 63) wsum[wv] = sc;            // wave totals
  __syncthreads();
  if (tid < 64) {
    int tw = (tid < 16) ? wsum[tid] : 0;
    #pragma unroll
    for (int off = 1; off < 16; off <<= 1) {
      const int v = __shfl_up(tw, off, 64);
      if (tid >= off) tw += v;
    }
    if (tid < 16) wsum[tid] = tw;          // inclusive wave prefix
  }
  __syncthreads();
  const int excl = sc - own + (wv ? wsum[wv - 1] : 0);
  lcur[tid] = excl;
  offT[blockIdx.x * (kBuckets + 1) + tid] = excl;          // coalesced
  if (tid == 0) offT[blockIdx.x * (kBuckets + 1) + kBuckets] = cnt;
  __syncthreads();

  // ---- rank + scatter into this block's bucket-grouped region ----
  int* myBin = binned + blockIdx.x * kEdgesPerBlock;
  #pragma unroll
  for (int k = 0; k < kEPT; ++k) {
    const int j = tid + k * 1024;
    if (j < cnt) {
      const int pos = atomicAdd(&lcur[ebk[k]], 1);  // LDS int atomic
      myBin[pos] = es[k] | (edl[k] << 17);
    }
  }
}

// ---------------------------------------------------------------------------
// Kernel 2: one block per bucket (1024 blocks = 2 full occupancy rounds),
// 1024 threads (16 waves), 2 blocks/CU.
//  0) segment map over the 256 block regions (scan of region lengths)
//  1) cooperative region copy binned->lsrc (4 threads/region) + deg[] hist
//  4) lane-strided 4-deep pipelined gather, fixed-point LDS atomics
//  5) accum -> bf16 mean rows via deg[] in hsAll (98 live, 112 allocated)
//  6) MFMA epilogue (waves 0..6): 16-node tiles, guard local<98.
// ---------------------------------------------------------------------------
__global__ __launch_bounds__(1024, 8) void gcn_aggregate(
    const int*   __restrict__ ws_in,
    const float* __restrict__ W,     // [64][64] row-major W[o][d]
    const float* __restrict__ b,     // [64]
    float*       __restrict__ out) { // [kNodes][64]
  const uint2* fb16 = (const uint2*)(ws_in + kWsFeat);
  const int* offT   = ws_in + kWsOff;
  const int* binned = ws_in + kWsBinned;

  // lsrc (8KB, phases 1-4) and hsAll (16.1KB, phases 5-6) share storage.
  __shared__ __align__(16) char uShared[112 * 72 * 2];   // 16128 B
  __shared__ int    accum[kBucketNodes * kAccStride];    // 26.7 KB fixed-point
  __shared__ int    deg[128];                            // per-dL degree
  __shared__ int    runL[kBinBlocks + 1];
  __shared__ int    runG[kBinBlocks];
  __shared__ int    ssm[kBinBlocks];
  __shared__ ushort Wb16[64 * 64];                 // 8 KB, natural W[o][d]
  __shared__ float  bsh[64];
  int*    lsrc  = (int*)uShared;
  ushort* hsAll = (ushort*)uShared;

  const int tid = threadIdx.x;
  const int bkt = blockIdx.x;

  if (tid < 128) deg[tid] = 0;
  for (int i = tid; i < 4096; i += 1024) Wb16[i] = (ushort)bf16rne(W[i]);
  if (tid < 64) bsh[tid] = b[tid];
  for (int i = tid; i < kBucketNodes * kAccStride; i += 1024) accum[i] = 0;

  // ---- 0) segment map over the 256 block regions ----
  if (tid < kBinBlocks) {
    const int o0 = offT[tid * (kBuckets + 1) + bkt];
    const int o1 = offT[tid * (kBuckets + 1) + bkt + 1];
    runG[tid] = tid * kEdgesPerBlock + o0;
    ssm[tid] = o1 - o0;
  }
  __syncthreads();
  if (tid < 64) {                        // wave-0 shfl scan, 4 elems/lane
    const int base = tid * 4;
    const int v0 = ssm[base], v1 = ssm[base + 1];
    const int v2 = ssm[base + 2], v3 = ssm[base + 3];
    const int p1 = v0 + v1, p2 = p1 + v2, tot = p2 + v3;
    int sc = tot;
    #pragma unroll
    for (int off = 1; off < 64; off <<= 1) {
      const int v = __shfl_up(sc, off, 64);
      if (tid >= off) sc += v;
    }
    const int ex = sc - tot;             // exclusive prefix of lane total
    runL[base]     = ex;
    runL[base + 1] = ex + v0;
    runL[base + 2] = ex + p1;
    runL[base + 3] = ex + p2;
    if (tid == 63) runL[kBinBlocks] = sc;
  }
  __syncthreads();

  int sz = runL[kBinBlocks];
  if (sz > kCap) sz = kCap;  // never hit for this dataset

  // ---- 1) cooperative region copy + degree histogram ----
  // Region r's edges: binned[runG[r] .. +len) -> lsrc[runL[r] .. +len).
  // 4 threads per region; mean len 4.6.
  {
    const int r  = tid >> 2;             // 0..255
    const int k0 = tid & 3;
    const int base = runL[r];
    const int glob = runG[r];
    const int len  = runL[r + 1] - base;
    for (int k = k0; k < len; k += 4) {
      const int p = base + k;
      if (p >= sz) break;                // only when bucket overflows kCap
      const unsigned w = (unsigned)binned[glob + k];
      lsrc[p] = (int)w;
      atomicAdd(&deg[w >> 17], 1);
    }
  }
  __syncthreads();

  // ---- 4) lane-strided 4-deep pipelined gather, LDS atomics ----
  const int wave = tid >> 6;
  const int lane = tid & 63;
  const int g = lane >> 4;   // slot within wave
  const int c = lane & 15;   // 8B chunk = feats {c,16+c,32+c,48+c}
  {
    const int slot = wave * 4 + g;           // 0..63
    int j = slot;
    for (; j + 192 < sz; j += 256) {
      const unsigned e0 = (unsigned)lsrc[j];
      const unsigned e1 = (unsigned)lsrc[j + 64];
      const unsigned e2 = (unsigned)lsrc[j + 128];
      const unsigned e3 = (unsigned)lsrc[j + 192];
      const uint2 v0 = fb16[(size_t)(e0 & 0x1FFFFu) * 16 + c];
      const uint2 v1 = fb16[(size_t)(e1 & 0x1FFFFu) * 16 + c];
      const uint2 v2 = fb16[(size_t)(e2 & 0x1FFFFu) * 16 + c];
      const uint2 v3 = fb16[(size_t)(e3 & 0x1FFFFu) * 16 + c];
      int* r0 = accum + (int)(e0 >> 17) * kAccStride + c;
      atomicAdd(r0 + 0,  (int)(__uint_as_float(v0.x << 16)          * kFxScale));
      atomicAdd(r0 + 16, (int)(__uint_as_float(v0.x & 0xffff0000u) * kFxScale));
      atomicAdd(r0 + 32, (int)(__uint_as_float(v0.y << 16)          * kFxScale));
      atomicAdd(r0 + 48, (int)(__uint_as_float(v0.y & 0xffff0000u) * kFxScale));
      int* r1 = accum + (int)(e1 >> 17) * kAccStride + c;
      atomicAdd(r1 + 0,  (int)(__uint_as_float(v1.x << 16)          * kFxScale));
      atomicAdd(r1 + 16, (int)(__uint_as_float(v1.x & 0xffff0000u) * kFxScale));
      atomicAdd(r1 + 32, (int)(__uint_as_float(v1.y << 16)          * kFxScale));
      atomicAdd(r1 + 48, (int)(__uint_as_float(v1.y & 0xffff0000u) * kFxScale));
      int* r2 = accum + (int)(e2 >> 17) * kAccStride + c;
      atomicAdd(r2 + 0,  (int)(__uint_as_float(v2.x << 16)          * kFxScale));
      atomicAdd(r2 + 16, (int)(__uint_as_float(v2.x & 0xffff0000u) * kFxScale));
      atomicAdd(r2 + 32, (int)(__uint_as_float(v2.y << 16)          * kFxScale));
      atomicAdd(r2 + 48, (int)(__uint_as_float(v2.y & 0xffff0000u) * kFxScale));
      int* r3 = accum + (int)(e3 >> 17) * kAccStride + c;
      atomicAdd(r3 + 0,  (int)(__uint_as_float(v3.x << 16)          * kFxScale));
      atomicAdd(r3 + 16, (int)(__uint_as_float(v3.x & 0xffff0000u) * kFxScale));
      atomicAdd(r3 + 32, (int)(__uint_as_float(v3.y << 16)          * kFxScale));
      atomicAdd(r3 + 48, (int)(__uint_as_float(v3.y & 0xffff0000u) * kFxScale));
    }
    for (; j < sz; j += 64) {               // remainder, <=3 per slot
      const unsigned e = (unsigned)lsrc[j];
      const uint2 v = fb16[(size_t)(e & 0x1FFFFu) * 16 + c];
      int* rp = accum + (int)(e >> 17) * kAccStride + c;
      atomicAdd(rp + 0,  (int)(__uint_as_float(v.x << 16)          * kFxScale));
      atomicAdd(rp + 16, (int)(__uint_as_float(v.x & 0xffff0000u) * kFxScale));
      atomicAdd(rp + 32, (int)(__uint_as_float(v.y << 16)          * kFxScale));
      atomicAdd(rp + 48, (int)(__uint_as_float(v.y & 0xffff0000u) * kFxScale));
    }
  }
  __syncthreads();

  // ---- 5) accum -> bf16 mean rows via deg[] (over dead lsrc) ----
  {
    const int nd = tid >> 3;          // 0..127; 98 live rows, 8 chunks each
    const int ch = tid & 7;
    if (nd < kBucketNodes) {
      const int dg = deg[nd];
      const float inv = 1.0f / (kFxScale * (float)(dg > 1 ? dg : 1));
      const int* arow = accum + nd * kAccStride + ch * 8;
      unsigned h[8];
      #pragma unroll
      for (int q = 0; q < 8; ++q) h[q] = bf16rne((float)arow[q] * inv);
      uint4 pk;
      pk.x = h[0] | (h[1] << 16);
      pk.y = h[2] | (h[3] << 16);
      pk.z = h[4] | (h[5] << 16);
      pk.w = h[6] | (h[7] << 16);
      *(uint4*)(hsAll + nd * 72 + ch * 8) = pk;
    } else {
      if (nd < 112) *(uint4*)(hsAll + nd * 72 + ch * 8) =
          make_uint4(0u, 0u, 0u, 0u);
    }
  }
  __syncthreads();

  // ---- 6) MFMA epilogue (waves 0..6): wave w -> locals [w*16, w*16+16) ----
  if (tid < 448) {
    const int w8   = tid >> 6;        // 0..6
    const int ln   = tid & 63;
    const int quad = ln >> 4;
    const int col  = ln & 15;
    const int n0 = bkt * kBucketNodes;

    const short8 af0 = *reinterpret_cast<const short8*>(
        hsAll + (w8 * 16 + col) * 72 + 0 * 32 + quad * 8);
    const short8 af1 = *reinterpret_cast<const short8*>(
        hsAll + (w8 * 16 + col) * 72 + 1 * 32 + quad * 8);

    #pragma unroll
    for (int ob = 0; ob < 4; ++ob) {
      const short8 bf0 = *reinterpret_cast<const short8*>(
          Wb16 + (ob * 16 + col) * 64 + 0 * 32 + quad * 8);
      const short8 bf1 = *reinterpret_cast<const short8*>(
          Wb16 + (ob * 16 + col) * 64 + 1 * 32 + quad * 8);
      floatx4 acc = {0.f, 0.f, 0.f, 0.f};
      acc = __builtin_amdgcn_mfma_f32_16x16x32_bf16(af0, bf0, acc, 0, 0, 0);
      acc = __builtin_amdgcn_mfma_f32_16x16x32_bf16(af1, bf1, acc, 0, 0, 0);

      const int o = ob * 16 + col;
      const float bo = bsh[o];
      #pragma unroll
      for (int r = 0; r < 4; ++r) {
        const int local = w8 * 16 + quad * 4 + r;
        const int node = n0 + local;
        if (local < kBucketNodes && node < kNodes) {
          const float v = acc[r] + bo;
          out[(size_t)node * 64 + o] = v > 0.0f ? v : 0.0f;
        }
      }
    }
  }
}

// ---------------------------------------------------------------------------
extern "C" void kernel_launch(void* const* d_in, const int* in_sizes, int n_in,
                              void* d_out, int out_size, void* d_ws, size_t ws_size,
                              hipStream_t stream) {
  const float* feature  = (const float*)d_in[0];
  const int*   edge_src = (const int*)  d_in[1];
  const int*   edge_dst = (const int*)  d_in[2];
  const float* W        = (const float*)d_in[3];
  const float* b        = (const float*)d_in[4];

  float* out = (float*)d_out;
  int*   ws  = (int*)d_ws;

  gcn_build<<<kBinBlocks, 1024, 0, stream>>>(feature, edge_src, edge_dst, ws);
  gcn_aggregate<<<kBuckets, 1024, 0, stream>>>(ws, W, b, out);
}